// Round 8
// baseline (67.205 us; speedup 1.0000x reference)
//
#include <hip/hip_runtime.h>
#include <hip/hip_bf16.h>
#include <math.h>

#define CIN   128
#define DDIM  64
#define KCB   512
#define HWSZ  4096
#define NPIX  131072
#define NOUTQ 8388608
#define XPAD  136   // shorts per pixel row in a wave's x/z slot

typedef short bf16x8 __attribute__((ext_vector_type(8)));
typedef float f32x4  __attribute__((ext_vector_type(4)));
typedef unsigned int u32x2 __attribute__((ext_vector_type(2)));

// d_ws layout (bytes). Requires ws_size >= 362496 (~354 KB).
#define WS_CBA  0        // bf16 -2c A-frags: 65536 B
#define WS_WA   65536    // bf16 W A-frags:   16384 B
#define WS_CBN  81920    // f32 ||c||^2:       2048 B
#define WS_PART 83968    // f32 partials[4096]:16384 B
#define WS_KB   100352   // u16 kbest[131072]:262144 B

__device__ __forceinline__ unsigned int bcu(float f){ union{float f;unsigned int u;}v; v.f=f; return v.u; }
__device__ __forceinline__ float bcf(unsigned int u){ union{unsigned int u;float f;}v; v.u=u; return v.f; }
__device__ __forceinline__ unsigned int pkbf(float a, float b){   // 2xf32 -> packed bf16 (RNE)
    union { __hip_bfloat162 h; unsigned int u; } v;
    v.h = __float22bfloat162_rn(make_float2(a, b));
    return v.u;
}

#define MFMA16(A, B, C) __builtin_amdgcn_mfma_f32_16x16x32_bf16((A), (B), (C), 0, 0, 0)

// ---------------------------------------------------------------------------
// k0: build global frag arrays in d_ws (same permutation math as verified R7
// LDS prologue, retargeted to global memory). grid 32 x 256.
// ---------------------------------------------------------------------------
__global__ __launch_bounds__(256) void vq_prep(
    const float* __restrict__ cb, const float* __restrict__ w,
    unsigned short* __restrict__ cbA, unsigned short* __restrict__ wA,
    float* __restrict__ cbn)
{
    const int gid = blockIdx.x * 256 + threadIdx.x;   // [0, 8192)
    {   // cbA: A[k][d] = -2*cb, one f32x4 -> u32x2 per thread
        int k = gid >> 4, dg = gid & 15;
        f32x4 v = *(const f32x4*)(cb + (size_t)k * DDIM + dg * 4);
        u32x2 pv = { pkbf(-2.f * v[0], -2.f * v[1]), pkbf(-2.f * v[2], -2.f * v[3]) };
        int ct = k >> 4, ks = dg >> 3, lhi = (dg >> 1) & 3, ll = (k & 15) | (lhi << 4);
        *(u32x2*)(cbA + ((ct * 2 + ks) * 64 + ll) * 8 + (dg & 1) * 4) = pv;
    }
    if (gid < 2048) {   // wA: A[d][c]
        int d = gid >> 5, cg = gid & 31;
        f32x4 v = *(const f32x4*)(w + (size_t)d * CIN + cg * 4);
        u32x2 pv = { pkbf(v[0], v[1]), pkbf(v[2], v[3]) };
        int dt = d >> 4, ks = cg >> 3, lhi = (cg >> 1) & 3, ll = (d & 15) | (lhi << 4);
        *(u32x2*)(wA + ((dt * 4 + ks) * 64 + ll) * 8 + (cg & 1) * 4) = pv;
    }
    if (gid < KCB) {    // ||c_k||^2 exact f32
        const f32x4* row = (const f32x4*)(cb + (size_t)gid * DDIM);
        float s = 0.f;
        #pragma unroll
        for (int j = 0; j < DDIM / 4; ++j) {
            f32x4 v = row[j];
            s = fmaf(v[0], v[0], s); s = fmaf(v[1], v[1], s);
            s = fmaf(v[2], v[2], s); s = fmaf(v[3], v[3], s);
        }
        cbn[gid] = s;
    }
}

// stage x (regs->bf16->own slot), 16-MFMA projection (W frags from L2),
// z roundtrip through the slot -> zb frags. Verified R7 semantics.
__device__ __forceinline__ void proj_tile(
    const float (&xr)[32], unsigned short* xrow,
    const unsigned short* __restrict__ wA, const float* __restrict__ bias,
    int lg, int klg, int l,
    f32x4& zA, f32x4& zB, f32x4& zC, f32x4& zD, bf16x8& zb0, bf16x8& zb1)
{
    #pragma unroll
    for (int j = 0; j < 8; ++j) {
        u32x2 pv = { pkbf(xr[4*j+0], xr[4*j+1]), pkbf(xr[4*j+2], xr[4*j+3]) };
        *(u32x2*)(xrow + lg * 32 + 4 * j) = pv;   // ds_write_b64
    }
    zA = *(const f32x4*)(bias +  0 + klg);
    zB = *(const f32x4*)(bias + 16 + klg);
    zC = *(const f32x4*)(bias + 32 + klg);
    zD = *(const f32x4*)(bias + 48 + klg);
    #pragma unroll
    for (int ks = 0; ks < 4; ++ks) {
        bf16x8 xf = *(const bf16x8*)(xrow + ks * 32 + lg * 8);
        bf16x8 w0 = *(const bf16x8*)(wA + ((0 * 4 + ks) * 64 + l) * 8);   // L2/L1-hot
        bf16x8 w1 = *(const bf16x8*)(wA + ((1 * 4 + ks) * 64 + l) * 8);
        bf16x8 w2 = *(const bf16x8*)(wA + ((2 * 4 + ks) * 64 + l) * 8);
        bf16x8 w3 = *(const bf16x8*)(wA + ((3 * 4 + ks) * 64 + l) * 8);
        zA = MFMA16(w0, xf, zA);
        zB = MFMA16(w1, xf, zB);
        zC = MFMA16(w2, xf, zC);
        zD = MFMA16(w3, xf, zD);
    }
    // z -> bf16 -> same slot row (same-wave LDS ordering via lgkmcnt)
    unsigned int* zr = (unsigned int*)xrow;
    u32x2 z0 = { pkbf(zA[0], zA[1]), pkbf(zA[2], zA[3]) };
    u32x2 z1 = { pkbf(zB[0], zB[1]), pkbf(zB[2], zB[3]) };
    u32x2 z2 = { pkbf(zC[0], zC[1]), pkbf(zC[2], zC[3]) };
    u32x2 z3 = { pkbf(zD[0], zD[1]), pkbf(zD[2], zD[3]) };
    *(u32x2*)(zr +  0 + lg * 2) = z0;
    *(u32x2*)(zr +  8 + lg * 2) = z1;
    *(u32x2*)(zr + 16 + lg * 2) = z2;
    *(u32x2*)(zr + 24 + lg * 2) = z3;
    zb0 = *(const bf16x8*)(xrow + lg * 8);        // d = lg*8 + e
    zb1 = *(const bf16x8*)(xrow + 32 + lg * 8);   // d = 32 + lg*8 + e
}

// ---------------------------------------------------------------------------
// k1: projection + argmin. 1024 blocks x 256 thr (4 independent waves, no
// barriers, no atomics). Wave = 32 adjacent pixels (two 16-px tiles).
// Outputs: kbest u16 per pixel + one f32 loss partial per wave
// (loss_px = score_best + ||z||^2  ==  ||z - c||^2).
// ---------------------------------------------------------------------------
__global__ __launch_bounds__(256, 4) void vq_scan(
    const float* __restrict__ x,      // [32][128][4096]
    const float* __restrict__ bias,   // [64]
    const unsigned short* __restrict__ cbA,
    const unsigned short* __restrict__ wA,
    const float* __restrict__ cbn,
    unsigned short* __restrict__ kb,
    float* __restrict__ part)
{
    __shared__ __align__(16) unsigned short sX[4 * 16 * XPAD];   // 17.4 KB

    const int t   = threadIdx.x;
    const int l   = t & 63;
    const int wv  = t >> 6;
    const int p16 = l & 15;
    const int lg  = l >> 4;
    const int klg = lg * 4;

    const int pixg = blockIdx.x * 128 + wv * 32;
    const int b   = pixg >> 12;
    const int hw0 = pixg & 4095;
    const float* xp = x + ((size_t)b * CIN + (size_t)lg * 32) * HWSZ + hw0 + p16;
    unsigned short* xrow = sX + wv * (16 * XPAD) + p16 * XPAD;

    float xr0[32], xr1[32];
    #pragma unroll
    for (int j = 0; j < 32; ++j) {       // paired loads: full 128B line per plane
        xr0[j] = xp[(size_t)j * HWSZ];
        xr1[j] = xp[(size_t)j * HWSZ + 16];
    }

    f32x4 zaA0, zaA1, zaA2, zaA3, zaB0, zaB1, zaB2, zaB3;
    bf16x8 zb00, zb01, zb10, zb11;
    proj_tile(xr0, xrow, wA, bias, lg, klg, l, zaA0, zaA1, zaA2, zaA3, zb00, zb01);
    proj_tile(xr1, xrow, wA, bias, lg, klg, l, zaB0, zaB1, zaB2, zaB3, zb10, zb11);

    // ---- score scan: frags straight from L2; packed-key argmin ----
    float rm00 = INFINITY, rm01 = INFINITY, rm10 = INFINITY, rm11 = INFINITY;
    #pragma unroll 4
    for (int ct = 0; ct < 32; ++ct) {
        f32x4 cinit = *(const f32x4*)(cbn + ct * 16 + klg);   // init = ||c||^2
        bf16x8 c0 = *(const bf16x8*)(cbA + ((ct * 2 + 0) * 64 + l) * 8);
        bf16x8 c1 = *(const bf16x8*)(cbA + ((ct * 2 + 1) * 64 + l) * 8);
        f32x4 a0 = MFMA16(c0, zb00, cinit); a0 = MFMA16(c1, zb01, a0);
        f32x4 a1 = MFMA16(c0, zb10, cinit); a1 = MFMA16(c1, zb11, a1);
        unsigned int kbse = (unsigned int)(ct * 16 + klg);
        rm00 = fminf(rm00, bcf((bcu(a0[0]) & 0xFFFFFE00u) | (kbse + 0)));
        rm01 = fminf(rm01, bcf((bcu(a0[1]) & 0xFFFFFE00u) | (kbse + 1)));
        rm00 = fminf(rm00, bcf((bcu(a0[2]) & 0xFFFFFE00u) | (kbse + 2)));
        rm01 = fminf(rm01, bcf((bcu(a0[3]) & 0xFFFFFE00u) | (kbse + 3)));
        rm10 = fminf(rm10, bcf((bcu(a1[0]) & 0xFFFFFE00u) | (kbse + 0)));
        rm11 = fminf(rm11, bcf((bcu(a1[1]) & 0xFFFFFE00u) | (kbse + 1)));
        rm10 = fminf(rm10, bcf((bcu(a1[2]) & 0xFFFFFE00u) | (kbse + 2)));
        rm11 = fminf(rm11, bcf((bcu(a1[3]) & 0xFFFFFE00u) | (kbse + 3)));
    }
    float rn0 = fminf(rm00, rm01);
    rn0 = fminf(rn0, __shfl_xor(rn0, 16, 64));
    rn0 = fminf(rn0, __shfl_xor(rn0, 32, 64));
    const int kbest0 = (int)(bcu(rn0) & 511u);
    float rn1 = fminf(rm10, rm11);
    rn1 = fminf(rn1, __shfl_xor(rn1, 16, 64));
    rn1 = fminf(rn1, __shfl_xor(rn1, 32, 64));
    const int kbest1 = (int)(bcu(rn1) & 511u);

    // ---- ||z||^2 per pixel (f32 accumulators, cross-lg reduce) ----
    float zn0 = 0.f, zn1 = 0.f;
    #pragma unroll
    for (int r = 0; r < 4; ++r) {
        zn0 = fmaf(zaA0[r], zaA0[r], zn0); zn0 = fmaf(zaA1[r], zaA1[r], zn0);
        zn0 = fmaf(zaA2[r], zaA2[r], zn0); zn0 = fmaf(zaA3[r], zaA3[r], zn0);
        zn1 = fmaf(zaB0[r], zaB0[r], zn1); zn1 = fmaf(zaB1[r], zaB1[r], zn1);
        zn1 = fmaf(zaB2[r], zaB2[r], zn1); zn1 = fmaf(zaB3[r], zaB3[r], zn1);
    }
    zn0 += __shfl_xor(zn0, 16, 64); zn0 += __shfl_xor(zn0, 32, 64);
    zn1 += __shfl_xor(zn1, 16, 64); zn1 += __shfl_xor(zn1, 32, 64);

    // ---- outputs: kbest (2B/px) + loss partial (1 f32/wave) ----
    if (l < 16) {
        kb[pixg + p16]      = (unsigned short)kbest0;
        kb[pixg + 16 + p16] = (unsigned short)kbest1;
    }
    // loss_px = score_best + ||z||^2; each value duplicated on 4 lanes -> *0.25
    float lv = 0.25f * ((rn0 + zn0) + (rn1 + zn1));
    #pragma unroll
    for (int off = 32; off > 0; off >>= 1)
        lv += __shfl_down(lv, off, 64);
    if (l == 0) part[blockIdx.x * 4 + wv] = lv;
}

// ---------------------------------------------------------------------------
// k2: scatter output + final loss reduce. 2048 blocks x 256 thr.
// Thread = (pixel, d-quarter): 16 stores, each wave instr = 256B contiguous.
// Block 0 / wave 0 reduces the 4096 partials -> loss (single writer).
// ---------------------------------------------------------------------------
__global__ __launch_bounds__(256, 8) void vq_out(
    const float* __restrict__ cb, const unsigned short* __restrict__ kb,
    const float* __restrict__ part, float* __restrict__ out,
    float* __restrict__ loss_slot)
{
    const int t   = threadIdx.x;
    const int bid = blockIdx.x;
    const int px  = ((bid >> 2) << 8) + t;    // 256 consecutive px per block
    const int dq  = bid & 3;                  // d-quarter
    const int b   = px >> 12;
    const int hw  = px & 4095;
    const int k   = kb[px];
    const f32x4* qr = (const f32x4*)(cb + (size_t)k * DDIM + dq * 16);   // L2-hot
    f32x4 q0 = qr[0], q1 = qr[1], q2 = qr[2], q3 = qr[3];
    size_t base = ((size_t)b * DDIM + dq * 16) * (size_t)HWSZ + hw;
    #pragma unroll
    for (int r = 0; r < 4; ++r) {
        out[base + (size_t)(r +  0) * HWSZ] = q0[r];
        out[base + (size_t)(r +  4) * HWSZ] = q1[r];
        out[base + (size_t)(r +  8) * HWSZ] = q2[r];
        out[base + (size_t)(r + 12) * HWSZ] = q3[r];
    }
    if (bid == 0 && t < 64) {
        float s = 0.f;
        #pragma unroll
        for (int j = 0; j < 64; ++j) s += part[t + j * 64];
        #pragma unroll
        for (int off = 32; off > 0; off >>= 1) s += __shfl_down(s, off, 64);
        if (t == 0) *loss_slot = s * (1.25f / (float)NOUTQ);
    }
}

extern "C" void kernel_launch(void* const* d_in, const int* in_sizes, int n_in,
                              void* d_out, int out_size, void* d_ws, size_t ws_size,
                              hipStream_t stream) {
    const float* x    = (const float*)d_in[0];   // [32,128,64,64]
    const float* w    = (const float*)d_in[1];   // [64,128]
    const float* bias = (const float*)d_in[2];   // [64]
    const float* cb   = (const float*)d_in[3];   // [512,64]
    float* out = (float*)d_out;                  // 8388608 quantized + 1 loss
    float* loss_slot = out + NOUTQ;

    char* ws = (char*)d_ws;                      // needs >= 362496 B
    unsigned short* cbA = (unsigned short*)(ws + WS_CBA);
    unsigned short* wA  = (unsigned short*)(ws + WS_WA);
    float*          cbn = (float*)(ws + WS_CBN);
    float*          prt = (float*)(ws + WS_PART);
    unsigned short* kbb = (unsigned short*)(ws + WS_KB);

    vq_prep<<<32,   256, 0, stream>>>(cb, w, cbA, wA, cbn);
    vq_scan<<<1024, 256, 0, stream>>>(x, bias, cbA, wA, cbn, kbb, prt);
    vq_out <<<2048, 256, 0, stream>>>(cb, kbb, prt, out, loss_slot);
}

// Round 9
// 55.940 us; speedup vs baseline: 1.2014x; 1.2014x over previous
//
#include <hip/hip_runtime.h>
#include <hip/hip_bf16.h>
#include <math.h>

#define CIN   128
#define DDIM  64
#define KCB   512
#define HWSZ  4096
#define NPIX  131072
#define NOUTQ 8388608
#define XPAD  136   // shorts per pixel row in a wave's x/z slot
#define NWAVE 8192  // one 16-px tile per wave

typedef short bf16x8 __attribute__((ext_vector_type(8)));
typedef float f32x4  __attribute__((ext_vector_type(4)));
typedef unsigned int u32x2 __attribute__((ext_vector_type(2)));

// d_ws layout (bytes). Requires ws_size >= 116736 (~114 KB).
#define WS_CBA  0        // bf16 -2c A-frags: 65536 B
#define WS_WA   65536    // bf16 W A-frags:   16384 B
#define WS_CBN  81920    // f32 ||c||^2:       2048 B
#define WS_PART 83968    // f32 partials[8192]: 32768 B

__device__ __forceinline__ unsigned int bcu(float f){ union{float f;unsigned int u;}v; v.f=f; return v.u; }
__device__ __forceinline__ float bcf(unsigned int u){ union{unsigned int u;float f;}v; v.u=u; return v.f; }
__device__ __forceinline__ unsigned int pkbf(float a, float b){   // 2xf32 -> packed bf16 (RNE)
    union { __hip_bfloat162 h; unsigned int u; } v;
    v.h = __float22bfloat162_rn(make_float2(a, b));
    return v.u;
}

#define MFMA16(A, B, C) __builtin_amdgcn_mfma_f32_16x16x32_bf16((A), (B), (C), 0, 0, 0)

// ---------------------------------------------------------------------------
// k0: build global frag arrays in d_ws (verified R8). grid 32 x 256.
// ---------------------------------------------------------------------------
__global__ __launch_bounds__(256) void vq_prep(
    const float* __restrict__ cb, const float* __restrict__ w,
    unsigned short* __restrict__ cbA, unsigned short* __restrict__ wA,
    float* __restrict__ cbn)
{
    const int gid = blockIdx.x * 256 + threadIdx.x;   // [0, 8192)
    {   // cbA: A[k][d] = -2*cb
        int k = gid >> 4, dg = gid & 15;
        f32x4 v = *(const f32x4*)(cb + (size_t)k * DDIM + dg * 4);
        u32x2 pv = { pkbf(-2.f * v[0], -2.f * v[1]), pkbf(-2.f * v[2], -2.f * v[3]) };
        int ct = k >> 4, ks = dg >> 3, lhi = (dg >> 1) & 3, ll = (k & 15) | (lhi << 4);
        *(u32x2*)(cbA + ((ct * 2 + ks) * 64 + ll) * 8 + (dg & 1) * 4) = pv;
    }
    if (gid < 2048) {   // wA: A[d][c]
        int d = gid >> 5, cg = gid & 31;
        f32x4 v = *(const f32x4*)(w + (size_t)d * CIN + cg * 4);
        u32x2 pv = { pkbf(v[0], v[1]), pkbf(v[2], v[3]) };
        int dt = d >> 4, ks = cg >> 3, lhi = (cg >> 1) & 3, ll = (d & 15) | (lhi << 4);
        *(u32x2*)(wA + ((dt * 4 + ks) * 64 + ll) * 8 + (cg & 1) * 4) = pv;
    }
    if (gid < KCB) {    // ||c_k||^2 exact f32
        const f32x4* row = (const f32x4*)(cb + (size_t)gid * DDIM);
        float s = 0.f;
        #pragma unroll
        for (int j = 0; j < DDIM / 4; ++j) {
            f32x4 v = row[j];
            s = fmaf(v[0], v[0], s); s = fmaf(v[1], v[1], s);
            s = fmaf(v[2], v[2], s); s = fmaf(v[3], v[3], s);
        }
        cbn[gid] = s;
    }
}

// stage x (regs->bf16->own slot), 16-MFMA projection (W frags from L2),
// z roundtrip through the slot -> zb frags. Verified R7/R8 semantics.
__device__ __forceinline__ void proj_tile(
    const float (&xr)[32], unsigned short* xrow,
    const unsigned short* __restrict__ wA, const float* __restrict__ bias,
    int lg, int klg, int l,
    f32x4& zA, f32x4& zB, f32x4& zC, f32x4& zD, bf16x8& zb0, bf16x8& zb1)
{
    #pragma unroll
    for (int j = 0; j < 8; ++j) {
        u32x2 pv = { pkbf(xr[4*j+0], xr[4*j+1]), pkbf(xr[4*j+2], xr[4*j+3]) };
        *(u32x2*)(xrow + lg * 32 + 4 * j) = pv;   // ds_write_b64
    }
    zA = *(const f32x4*)(bias +  0 + klg);
    zB = *(const f32x4*)(bias + 16 + klg);
    zC = *(const f32x4*)(bias + 32 + klg);
    zD = *(const f32x4*)(bias + 48 + klg);
    #pragma unroll
    for (int ks = 0; ks < 4; ++ks) {
        bf16x8 xf = *(const bf16x8*)(xrow + ks * 32 + lg * 8);
        bf16x8 w0 = *(const bf16x8*)(wA + ((0 * 4 + ks) * 64 + l) * 8);   // L2-hot
        bf16x8 w1 = *(const bf16x8*)(wA + ((1 * 4 + ks) * 64 + l) * 8);
        bf16x8 w2 = *(const bf16x8*)(wA + ((2 * 4 + ks) * 64 + l) * 8);
        bf16x8 w3 = *(const bf16x8*)(wA + ((3 * 4 + ks) * 64 + l) * 8);
        zA = MFMA16(w0, xf, zA);
        zB = MFMA16(w1, xf, zB);
        zC = MFMA16(w2, xf, zC);
        zD = MFMA16(w3, xf, zD);
    }
    // z -> bf16 -> same slot row (same-wave LDS ordering via lgkmcnt)
    unsigned int* zr = (unsigned int*)xrow;
    u32x2 z0 = { pkbf(zA[0], zA[1]), pkbf(zA[2], zA[3]) };
    u32x2 z1 = { pkbf(zB[0], zB[1]), pkbf(zB[2], zB[3]) };
    u32x2 z2 = { pkbf(zC[0], zC[1]), pkbf(zC[2], zC[3]) };
    u32x2 z3 = { pkbf(zD[0], zD[1]), pkbf(zD[2], zD[3]) };
    *(u32x2*)(zr +  0 + lg * 2) = z0;
    *(u32x2*)(zr +  8 + lg * 2) = z1;
    *(u32x2*)(zr + 16 + lg * 2) = z2;
    *(u32x2*)(zr + 24 + lg * 2) = z3;
    zb0 = *(const bf16x8*)(xrow + lg * 8);        // d = lg*8 + e
    zb1 = *(const bf16x8*)(xrow + 32 + lg * 8);   // d = 32 + lg*8 + e
}

// ---------------------------------------------------------------------------
// k1: full per-wave pipeline, ONE 16-px tile per wave (single x-latency
// window: 32 loads/lane issued together). 2048 blocks x 256 thr = 8192
// waves, no barriers, no atomics. Fused gather/store/loss (R7-verified).
// ---------------------------------------------------------------------------
__global__ __launch_bounds__(256, 4) void vq_scan_out(
    const float* __restrict__ x,      // [32][128][4096]
    const float* __restrict__ bias,   // [64]
    const unsigned short* __restrict__ cbA,
    const unsigned short* __restrict__ wA,
    const float* __restrict__ cbn,
    const float* __restrict__ cb,
    float* __restrict__ out,          // [32][64][4096]
    float* __restrict__ part)         // [8192]
{
    __shared__ __align__(16) unsigned short sX[4 * 16 * XPAD];   // 17.4 KB

    const int t   = threadIdx.x;
    const int l   = t & 63;
    const int wv  = t >> 6;
    const int p16 = l & 15;
    const int lg  = l >> 4;
    const int klg = lg * 4;

    const int wid  = blockIdx.x * 4 + wv;
    const int pixg = wid * 16;
    const int b    = pixg >> 12;
    const int hw0  = pixg & 4095;
    const float* xp = x + ((size_t)b * CIN + (size_t)lg * 32) * HWSZ + hw0 + p16;
    unsigned short* xrow = sX + wv * (16 * XPAD) + p16 * XPAD;

    // ---- single x window: all 32 loads issued back-to-back ----
    float xr[32];
    #pragma unroll
    for (int j = 0; j < 32; ++j) xr[j] = xp[(size_t)j * HWSZ];

    f32x4 zA, zB, zC, zD;
    bf16x8 zb0, zb1;
    proj_tile(xr, xrow, wA, bias, lg, klg, l, zA, zB, zC, zD, zb0, zb1);

    // ---- score scan: frags from L2; packed-key argmin (R7/R8-verified) ----
    float rm0 = INFINITY, rm1 = INFINITY;
    #pragma unroll 4
    for (int ct = 0; ct < 32; ++ct) {
        f32x4 cinit = *(const f32x4*)(cbn + ct * 16 + klg);   // init = ||c||^2
        bf16x8 c0 = *(const bf16x8*)(cbA + ((ct * 2 + 0) * 64 + l) * 8);
        bf16x8 c1 = *(const bf16x8*)(cbA + ((ct * 2 + 1) * 64 + l) * 8);
        f32x4 a0 = MFMA16(c0, zb0, cinit);
        a0 = MFMA16(c1, zb1, a0);
        unsigned int kbse = (unsigned int)(ct * 16 + klg);
        rm0 = fminf(rm0, bcf((bcu(a0[0]) & 0xFFFFFE00u) | (kbse + 0)));
        rm1 = fminf(rm1, bcf((bcu(a0[1]) & 0xFFFFFE00u) | (kbse + 1)));
        rm0 = fminf(rm0, bcf((bcu(a0[2]) & 0xFFFFFE00u) | (kbse + 2)));
        rm1 = fminf(rm1, bcf((bcu(a0[3]) & 0xFFFFFE00u) | (kbse + 3)));
    }
    float rn = fminf(rm0, rm1);
    rn = fminf(rn, __shfl_xor(rn, 16, 64));
    rn = fminf(rn, __shfl_xor(rn, 32, 64));
    const int kbest = (int)(bcu(rn) & 511u);

    // ---- gather winner (exact f32), store, exact-f32 loss partial ----
    const float* qrow = cb + (size_t)kbest * DDIM;   // L2-hot
    f32x4 q0 = *(const f32x4*)(qrow +  0 + klg);
    f32x4 q1 = *(const f32x4*)(qrow + 16 + klg);
    f32x4 q2 = *(const f32x4*)(qrow + 32 + klg);
    f32x4 q3 = *(const f32x4*)(qrow + 48 + klg);
    float lsum = 0.f;
    size_t ob = ((size_t)b * DDIM + klg) * (size_t)HWSZ + hw0 + p16;
    #pragma unroll
    for (int r = 0; r < 4; ++r) {
        float e;
        e = q0[r] - zA[r]; lsum = fmaf(e, e, lsum);
        e = q1[r] - zB[r]; lsum = fmaf(e, e, lsum);
        e = q2[r] - zC[r]; lsum = fmaf(e, e, lsum);
        e = q3[r] - zD[r]; lsum = fmaf(e, e, lsum);
        out[ob + (size_t)(r +  0) * HWSZ] = q0[r];
        out[ob + (size_t)(r + 16) * HWSZ] = q1[r];
        out[ob + (size_t)(r + 32) * HWSZ] = q2[r];
        out[ob + (size_t)(r + 48) * HWSZ] = q3[r];
    }

    // ---- one partial per wave (no atomics) ----
    #pragma unroll
    for (int off = 32; off > 0; off >>= 1)
        lsum += __shfl_down(lsum, off, 64);
    if (l == 0) part[wid] = lsum;
}

// ---------------------------------------------------------------------------
// k2: final loss reduce, 1 block x 256 thr (single writer, deterministic).
// ---------------------------------------------------------------------------
__global__ __launch_bounds__(256) void vq_loss(
    const float* __restrict__ part, float* __restrict__ loss_slot)
{
    __shared__ float sW[4];
    const int t = threadIdx.x;
    const f32x4* p4 = (const f32x4*)part;          // 2048 f32x4
    float s = 0.f;
    #pragma unroll
    for (int j = 0; j < 8; ++j) {
        f32x4 v = p4[t + j * 256];
        s += v[0] + v[1] + v[2] + v[3];
    }
    #pragma unroll
    for (int off = 32; off > 0; off >>= 1) s += __shfl_down(s, off, 64);
    if ((t & 63) == 0) sW[t >> 6] = s;
    __syncthreads();
    if (t == 0)
        *loss_slot = (sW[0] + sW[1] + sW[2] + sW[3]) * (1.25f / (float)NOUTQ);
}

extern "C" void kernel_launch(void* const* d_in, const int* in_sizes, int n_in,
                              void* d_out, int out_size, void* d_ws, size_t ws_size,
                              hipStream_t stream) {
    const float* x    = (const float*)d_in[0];   // [32,128,64,64]
    const float* w    = (const float*)d_in[1];   // [64,128]
    const float* bias = (const float*)d_in[2];   // [64]
    const float* cb   = (const float*)d_in[3];   // [512,64]
    float* out = (float*)d_out;                  // 8388608 quantized + 1 loss
    float* loss_slot = out + NOUTQ;

    char* ws = (char*)d_ws;                      // needs >= 116736 B
    unsigned short* cbA = (unsigned short*)(ws + WS_CBA);
    unsigned short* wA  = (unsigned short*)(ws + WS_WA);
    float*          cbn = (float*)(ws + WS_CBN);
    float*          prt = (float*)(ws + WS_PART);

    vq_prep    <<<32,   256, 0, stream>>>(cb, w, cbA, wA, cbn);
    vq_scan_out<<<2048, 256, 0, stream>>>(x, bias, cbA, wA, cbn, cb, out, prt);
    vq_loss    <<<1,    256, 0, stream>>>(prt, loss_slot);
}